// Round 1
// baseline (304.596 us; speedup 1.0000x reference)
//
#include <hip/hip_runtime.h>
#include <math.h>

// Problem constants
#define N_IMG       16
#define N_CH        3
#define PLANES      (N_IMG * N_CH)      // 48 (image,channel) planes
#define BINS        64                  // HIST_BIN = 192/3
#define PLANE_ELEMS (1024 * 1024)       // elements per plane
#define PLANE_VEC   (PLANE_ELEMS / 4)   // float4 count per plane = 262144
#define BLOCKS_PER_PLANE 32
#define HIST_THREADS 256

// MLP dims
#define C0 192
#define C1 128
#define C2 32
// params offsets
#define OFF_W0 0
#define OFF_B0 (C0 * C1)                  // 24576
#define OFF_W1 (OFF_B0 + C1)              // 24704
#define OFF_B1 (OFF_W1 + C1 * C2)         // 28800
#define OFF_G  (OFF_B1 + C2)              // 28832

// ---------------------------------------------------------------------------
// Kernel 1: per-plane 64-bin histogram.
// LDS layout: 64 bins x 64 lane-copies (16 KB). Lane l only touches copy l:
//   addr = bin*64 + lane  -> bank = lane % 32 (2-way aliasing across wave64,
//   which is free). Cross-wave same-lane collisions resolved by LDS atomics.
// ---------------------------------------------------------------------------
__global__ __launch_bounds__(HIST_THREADS) void hist_kernel(
    const float4* __restrict__ img, unsigned int* __restrict__ g_hist)
{
    __shared__ unsigned int h[BINS * 64];   // [bin][lane]

    const int tid  = threadIdx.x;
    const int lane = tid & 63;

    for (int i = tid; i < BINS * 64; i += HIST_THREADS) h[i] = 0u;
    __syncthreads();

    const int plane = blockIdx.y;
    const float4* base = img + (size_t)plane * PLANE_VEC;

    const int per_block = PLANE_VEC / BLOCKS_PER_PLANE;   // 8192 float4
    const int start = blockIdx.x * per_block;
    const int end   = start + per_block;

    for (int i = start + tid; i < end; i += HIST_THREADS) {
        float4 v = base[i];
        // exactly matches jnp: clip((x*64).astype(int32), 0, 63)
        int b0 = min(max(__float2int_rz(v.x * 64.0f), 0), 63);
        int b1 = min(max(__float2int_rz(v.y * 64.0f), 0), 63);
        int b2 = min(max(__float2int_rz(v.z * 64.0f), 0), 63);
        int b3 = min(max(__float2int_rz(v.w * 64.0f), 0), 63);
        atomicAdd(&h[b0 * 64 + lane], 1u);
        atomicAdd(&h[b1 * 64 + lane], 1u);
        atomicAdd(&h[b2 * 64 + lane], 1u);
        atomicAdd(&h[b3 * 64 + lane], 1u);
    }
    __syncthreads();

    // Reduce 64 lane-copies per bin; one global atomic per bin per block.
    if (tid < BINS) {
        unsigned int s = 0;
        #pragma unroll
        for (int l = 0; l < 64; ++l) s += h[tid * 64 + l];
        atomicAdd(&g_hist[plane * BINS + tid], s);
    }
}

// ---------------------------------------------------------------------------
// Kernel 2: tiny MLP. hist (48*64 u32, == feat[16][192]) -> 128 relu -> 32,
// sigmoid(global + x). One block, 512 threads; everything fp32.
// ---------------------------------------------------------------------------
__global__ __launch_bounds__(512) void mlp_kernel(
    const unsigned int* __restrict__ g_hist,
    const float* __restrict__ params,
    float* __restrict__ out)
{
    __shared__ float feat[N_IMG * C0];   // 3072 floats (== PLANES*BINS)
    __shared__ float h1[N_IMG * C1];     // 2048 floats

    const int tid = threadIdx.x;

    for (int i = tid; i < N_IMG * C0; i += 512)
        feat[i] = (float)g_hist[i];       // counts < 2^24: exact
    __syncthreads();

    const float* W0 = params + OFF_W0;   // [192][128] row-major
    const float* b0 = params + OFF_B0;
    const float* W1 = params + OFF_W1;   // [128][32]
    const float* b1 = params + OFF_B1;
    const float  g  = params[OFF_G];

    // layer 0 + relu: 2048 outputs, 4 per thread
    for (int t = tid; t < N_IMG * C1; t += 512) {
        const int n = t >> 7, j = t & 127;
        float acc = b0[j];
        const float* f = feat + n * C0;
        #pragma unroll 8
        for (int i = 0; i < C0; ++i)
            acc = fmaf(f[i], W0[i * C1 + j], acc);
        h1[t] = fmaxf(acc, 0.0f);
    }
    __syncthreads();

    // layer 1 + sigmoid: 512 outputs, 1 per thread
    {
        const int n = tid >> 5, k = tid & 31;
        float acc = b1[k];
        const float* hh = h1 + n * C1;
        #pragma unroll 8
        for (int j = 0; j < C1; ++j)
            acc = fmaf(hh[j], W1[j * C2 + k], acc);
        float x = g + acc;
        out[tid] = 1.0f / (1.0f + expf(-x));
    }
}

extern "C" void kernel_launch(void* const* d_in, const int* in_sizes, int n_in,
                              void* d_out, int out_size, void* d_ws, size_t ws_size,
                              hipStream_t stream)
{
    const float* img    = (const float*)d_in[0];
    const float* params = (const float*)d_in[1];
    float* out          = (float*)d_out;
    unsigned int* g_hist = (unsigned int*)d_ws;   // 48*64 u32 = 12 KB

    // ws is re-poisoned to 0xAA before every launch — must re-zero each call.
    hipMemsetAsync(g_hist, 0, PLANES * BINS * sizeof(unsigned int), stream);

    dim3 grid(BLOCKS_PER_PLANE, PLANES);
    hist_kernel<<<grid, HIST_THREADS, 0, stream>>>((const float4*)img, g_hist);
    mlp_kernel<<<1, 512, 0, stream>>>(g_hist, params, out);
}